// Round 7
// baseline (518.921 us; speedup 1.0000x reference)
//
#include <hip/hip_runtime.h>
#include <math.h>

// MFMA + butterfly-reduce fused autoencoder fwd + Jacobians.
// Per wave: 64 samples (two 32-sample groups).
// Layer2 (16x16 GEMV batch over 32 samples): v_mfma_f32_32x32x16_bf16,
//   A = [W2 ; 0] (32x16 bf16 prepacked frags), B = activations built in-layout
//   (lane = (sample = lane&31, k-half h = lane>>5) holds k = 8h..8h+7).
//   C/D: col=lane&31, row=(reg&3)+8*(reg>>2)+4*h (verified m74/m101).
// Layer3 (2 outputs): NOT worth an MFMA (2/32 useful rows) -- per-lane 8-term
//   FMA partials + one shfl_xor(32) butterfly per output. This drops the
//   b3frag shuffle dance, 3 f32x16 accumulators, and makes outputs valid in
//   ALL lanes (theta feeds dec directly, stores split across h-halves).
// R7: __launch_bounds__(256,8) forces <=64 VGPR -> 8 waves/SIMD. R6 showed
// runtime tracks occupancy (VGPR 56/80/92 -> occ 39/26/18.5% -> 89/68/76us).

typedef float  f32x16 __attribute__((ext_vector_type(16)));
typedef short  bf16x8 __attribute__((ext_vector_type(8)));

__device__ __forceinline__ unsigned short f2bf1(float f) {   // RNE (prep only)
    unsigned u = __builtin_bit_cast(unsigned, f);
    u += 0x7FFFu + ((u >> 16) & 1u);
    return (unsigned short)(u >> 16);
}

// packed truncating f32->bf16 pair: 1 x v_perm_b32 (a -> low half)
__device__ __forceinline__ unsigned packbf(float a, float b) {
    return __builtin_amdgcn_perm(__builtin_bit_cast(unsigned, b),
                                 __builtin_bit_cast(unsigned, a), 0x07060302u);
}

__device__ __forceinline__ bf16x8 pack8(const float* v) {
    union { unsigned u[4]; bf16x8 f; } x;
    x.u[0] = packbf(v[0], v[1]); x.u[1] = packbf(v[2], v[3]);
    x.u[2] = packbf(v[4], v[5]); x.u[3] = packbf(v[6], v[7]);
    return x.f;
}

__device__ __forceinline__ void activ(float z, float& sp, float& sg) {
    float e  = __expf(-fabsf(z));             // shared by softplus & sigmoid
    float iv = __builtin_amdgcn_rcpf(1.0f + e);
    sg = (z >= 0.0f) ? iv : e * iv;           // sigmoid(z)
    sp = fmaxf(z, 0.0f) + __logf(1.0f + e);   // stable softplus
}

// ---- ws layout (float offsets) ----
// encL1 [64][24] @0 (wa[8] wb[8] b[8])   decL1 @1536
// encB2 [64][8] @3072   decB2 @3584
// A2 frags @4096: A2e (64 lanes x 8 shorts) | A2d  (512 floats total)
// encW3 [64][16] @4608 (w3row0[8] w3row1[8] per lane, C-layout rows)
// decW3 @5632    (total 6656 floats = 26.6 KB)
__global__ void prep_kernel(
    const float* __restrict__ ew1, const float* __restrict__ eb1,
    const float* __restrict__ ew2, const float* __restrict__ eb2,
    const float* __restrict__ ew3,
    const float* __restrict__ dw1, const float* __restrict__ db1,
    const float* __restrict__ dw2, const float* __restrict__ db2,
    const float* __restrict__ dw3,
    float* __restrict__ ws)
{
    const int t = threadIdx.x;
    if (t >= 64) return;
    const int h = t >> 5, m = t & 31;
    unsigned short* frag = (unsigned short*)(ws + 4096);
#pragma unroll
    for (int jj = 0; jj < 8; ++jj) {
        const int j = 8 * h + jj;
        ws[t*24 + jj]             = ew1[2*j];
        ws[t*24 + 8 + jj]         = ew1[2*j + 1];
        ws[t*24 + 16 + jj]        = eb1[j];
        ws[1536 + t*24 + jj]      = dw1[2*j];
        ws[1536 + t*24 + 8 + jj]  = dw1[2*j + 1];
        ws[1536 + t*24 + 16 + jj] = db1[j];
        frag[t*8 + jj]       = (m < 16) ? f2bf1(ew2[m*16 + j]) : (unsigned short)0;
        frag[512 + t*8 + jj] = (m < 16) ? f2bf1(dw2[m*16 + j]) : (unsigned short)0;
    }
#pragma unroll
    for (int r = 0; r < 8; ++r) {
        const int i = (r & 3) + 8 * (r >> 2) + 4 * h;   // C-layout row for reg r
        ws[3072 + t*8 + r] = eb2[i];
        ws[3584 + t*8 + r] = db2[i];
        ws[4608 + t*16 + r]     = ew3[i];        // w3[0, i]
        ws[4608 + t*16 + 8 + r] = ew3[16 + i];   // w3[1, i]
        ws[5632 + t*16 + r]     = dw3[i];
        ws[5632 + t*16 + 8 + r] = dw3[16 + i];
    }
}

__device__ __forceinline__ void mlp_mfma(
    const float* __restrict__ L1, const float* __restrict__ B2,
    const float* __restrict__ W3, bf16x8 A2, float b30, float b31,
    float x0, float x1,
    float& o0, float& o1, float& J00, float& J01, float& J10, float& J11)
{
    float h1[8], ta[8], tb[8];
#pragma unroll
    for (int jj = 0; jj < 8; ++jj) {
        float wa = L1[jj], wb = L1[8 + jj], bb = L1[16 + jj];
        float z = fmaf(wa, x0, fmaf(wb, x1, bb));
        float sp, sg; activ(z, sp, sg);
        h1[jj] = sp; ta[jj] = sg * wa; tb[jj] = sg * wb;
    }
    bf16x8 Bh = pack8(h1), Bta = pack8(ta), Btb = pack8(tb);
    f32x16 Z;
#pragma unroll
    for (int r = 0; r < 16; ++r) Z[r] = 0.0f;

    f32x16 zc = __builtin_amdgcn_mfma_f32_32x32x16_bf16(A2, Bh, Z, 0, 0, 0);
    float sp2[8], sg2[8];
#pragma unroll
    for (int r = 0; r < 8; ++r) {
        float z = zc[r] + B2[r];
        activ(z, sp2[r], sg2[r]);
    }
    f32x16 ua = __builtin_amdgcn_mfma_f32_32x32x16_bf16(A2, Bta, Z, 0, 0, 0);

    // layer-3 outputs: per-lane partial over this half's 8 rows + butterfly
    float a0 = 0.0f, a1 = 0.0f;
#pragma unroll
    for (int r = 0; r < 8; ++r) {
        a0 = fmaf(W3[r], sp2[r], a0);
        a1 = fmaf(W3[8 + r], sp2[r], a1);
    }
    o0 = a0 + __shfl_xor(a0, 32) + b30;
    o1 = a1 + __shfl_xor(a1, 32) + b31;

    float sa[8];
#pragma unroll
    for (int r = 0; r < 8; ++r) sa[r] = sg2[r] * ua[r];
    f32x16 ub = __builtin_amdgcn_mfma_f32_32x32x16_bf16(A2, Btb, Z, 0, 0, 0);

    float p0 = 0.0f, p1 = 0.0f;
#pragma unroll
    for (int r = 0; r < 8; ++r) {
        p0 = fmaf(W3[r], sa[r], p0);
        p1 = fmaf(W3[8 + r], sa[r], p1);
    }
    J00 = p0 + __shfl_xor(p0, 32);
    J10 = p1 + __shfl_xor(p1, 32);

    float sb[8];
#pragma unroll
    for (int r = 0; r < 8; ++r) sb[r] = sg2[r] * ub[r];
    float q0 = 0.0f, q1 = 0.0f;
#pragma unroll
    for (int r = 0; r < 8; ++r) {
        q0 = fmaf(W3[r], sb[r], q0);
        q1 = fmaf(W3[8 + r], sb[r], q1);
    }
    J01 = q0 + __shfl_xor(q0, 32);
    J11 = q1 + __shfl_xor(q1, 32);
}

__device__ __forceinline__ void do_group(
    const float* __restrict__ q, float* __restrict__ out, int n, int sbase,
    int s32, int h,
    const float* __restrict__ encL1, const float* __restrict__ decL1,
    const float* __restrict__ encB2, const float* __restrict__ decB2,
    const float* __restrict__ encW3, const float* __restrict__ decW3,
    bf16x8 A2e, bf16x8 A2d,
    float eb30, float eb31, float db30, float db31)
{
    const int sample = sbase + s32;
    const int sidx = sample < n ? sample : n - 1;

    const float2 qv = ((const float2*)q)[sidx];
    const float x = qv.x, y = qv.y;

    float th0, th1, eJ00, eJ01, eJ10, eJ11;
    mlp_mfma(encL1, encB2, encW3, A2e, eb30, eb31, x, y,
             th0, th1, eJ00, eJ01, eJ10, eJ11);
    // th/eJ valid in ALL lanes (butterfly) -> feeds dec directly

    float qh0, qh1, dJ00, dJ01, dJ10, dJ11;
    mlp_mfma(decL1, decB2, decW3, A2d, db30, db31, th0, th1,
             qh0, qh1, dJ00, dJ01, dJ10, dJ11);

    if (sample < n) {
        const size_t nn = (size_t)n;
        if (h == 0) {
            ((float2*)(out))[sample]          = make_float2(th0, th1);
            ((float4*)(out + 2 * nn))[sample] = make_float4(eJ00, eJ01, eJ10, eJ11);
        } else {
            const float r2   = fmaf(x, x, y * y);
            const float iv   = __builtin_amdgcn_rcpf(r2);
            const float rinv = __builtin_amdgcn_rsqf(r2 + 1e-8f);
            ((float2*)(out + 6 * nn))[sample]  = make_float2(qh0, qh1);
            ((float4*)(out + 8 * nn))[sample]  = make_float4(dJ00, dJ01, dJ10, dJ11);
            ((float4*)(out + 12 * nn))[sample] = make_float4(-y * iv, x * iv, x * rinv, y * rinv);
        }
    }
}

__global__ __launch_bounds__(256, 8) void ae_mfma_kernel(
    const float* __restrict__ q,
    const float* __restrict__ eb3, const float* __restrict__ db3,
    const float* __restrict__ ws, float* __restrict__ out, int n)
{
    const int lane = threadIdx.x & 63;
    const int w = blockIdx.x * 4 + (threadIdx.x >> 6);
    const int s32 = lane & 31, h = lane >> 5;
    const long base = (long)w * 64;            // 64 samples per wave
    if (base >= n) return;                     // wave-uniform exit

    const float* encL1 = ws + (size_t)lane * 24;
    const float* decL1 = ws + 1536 + (size_t)lane * 24;
    const float* encB2 = ws + 3072 + (size_t)lane * 8;
    const float* decB2 = ws + 3584 + (size_t)lane * 8;
    const float* encW3 = ws + 4608 + (size_t)lane * 16;
    const float* decW3 = ws + 5632 + (size_t)lane * 16;
    const bf16x8* fr = (const bf16x8*)(ws + 4096);
    const bf16x8 A2e = fr[lane], A2d = fr[64 + lane];
    const float eb30 = eb3[0], eb31 = eb3[1];
    const float db30 = db3[0], db31 = db3[1];

    do_group(q, out, n, (int)base, s32, h, encL1, decL1, encB2, decB2,
             encW3, decW3, A2e, A2d, eb30, eb31, db30, db31);
    if (base + 32 < n)
        do_group(q, out, n, (int)base + 32, s32, h, encL1, decL1, encB2, decB2,
                 encW3, decW3, A2e, A2d, eb30, eb31, db30, db31);
}

extern "C" void kernel_launch(void* const* d_in, const int* in_sizes, int n_in,
                              void* d_out, int out_size, void* d_ws, size_t ws_size,
                              hipStream_t stream)
{
    const float* q   = (const float*)d_in[0];
    const float* ew1 = (const float*)d_in[1];
    const float* eb1 = (const float*)d_in[2];
    const float* ew2 = (const float*)d_in[3];
    const float* eb2 = (const float*)d_in[4];
    const float* ew3 = (const float*)d_in[5];
    const float* eb3 = (const float*)d_in[6];
    const float* dw1 = (const float*)d_in[7];
    const float* db1 = (const float*)d_in[8];
    const float* dw2 = (const float*)d_in[9];
    const float* db2 = (const float*)d_in[10];
    const float* dw3 = (const float*)d_in[11];
    const float* db3 = (const float*)d_in[12];

    const int n = in_sizes[0] / 2;
    float* ws = (float*)d_ws;

    prep_kernel<<<1, 64, 0, stream>>>(ew1, eb1, ew2, eb2, ew3,
                                      dw1, db1, dw2, db2, dw3, ws);

    const int waves  = (n + 63) / 64;
    const int blocks = (waves + 3) / 4;
    ae_mfma_kernel<<<blocks, 256, 0, stream>>>(q, eb3, db3, ws, (float*)d_out, n);
}

// Round 8
// 160.268 us; speedup vs baseline: 3.2378x; 3.2378x over previous
//
#include <hip/hip_runtime.h>
#include <math.h>

// MFMA + butterfly-reduce fused autoencoder fwd + Jacobians.
// Per wave: 64 samples (two 32-sample groups).
// Layer2 (16x16 GEMV batch over 32 samples): v_mfma_f32_32x32x16_bf16,
//   A = [W2 ; 0] (32x16 bf16 prepacked frags), B = activations built in-layout
//   (lane = (sample = lane&31, k-half h = lane>>5) holds k = 8h..8h+7).
//   C/D: col=lane&31, row=(reg&3)+8*(reg>>2)+4*h (verified m74/m101).
// Layer3 (2 outputs): per-lane 8-term FMA partials + one shfl_xor(32)
//   butterfly per output (2/32 MFMA rows would be useful -- not worth it).
//   Outputs valid in ALL lanes -> theta feeds dec directly, stores split
//   across h-halves.
// R8: natural register allocation (__launch_bounds__(256) only). R7 proved
// forcing 8 waves/EU (32 VGPR) spills: FETCH 4->478MB, dur 441us. R5-R6
// showed best runtime at the allocator's own ~80 VGPR choice.

typedef float  f32x16 __attribute__((ext_vector_type(16)));
typedef short  bf16x8 __attribute__((ext_vector_type(8)));

__device__ __forceinline__ unsigned short f2bf1(float f) {   // RNE (prep only)
    unsigned u = __builtin_bit_cast(unsigned, f);
    u += 0x7FFFu + ((u >> 16) & 1u);
    return (unsigned short)(u >> 16);
}

// packed truncating f32->bf16 pair: 1 x v_perm_b32 (a -> low half)
__device__ __forceinline__ unsigned packbf(float a, float b) {
    return __builtin_amdgcn_perm(__builtin_bit_cast(unsigned, b),
                                 __builtin_bit_cast(unsigned, a), 0x07060302u);
}

__device__ __forceinline__ bf16x8 pack8(const float* v) {
    union { unsigned u[4]; bf16x8 f; } x;
    x.u[0] = packbf(v[0], v[1]); x.u[1] = packbf(v[2], v[3]);
    x.u[2] = packbf(v[4], v[5]); x.u[3] = packbf(v[6], v[7]);
    return x.f;
}

__device__ __forceinline__ void activ(float z, float& sp, float& sg) {
    float e  = __expf(-fabsf(z));             // shared by softplus & sigmoid
    float iv = __builtin_amdgcn_rcpf(1.0f + e);
    sg = (z >= 0.0f) ? iv : e * iv;           // sigmoid(z)
    sp = fmaxf(z, 0.0f) + __logf(1.0f + e);   // stable softplus
}

// ---- ws layout (float offsets) ----
// encL1 [64][24] @0 (wa[8] wb[8] b[8])   decL1 @1536
// encB2 [64][8] @3072   decB2 @3584
// A2 frags @4096: A2e (64 lanes x 8 shorts) | A2d  (512 floats total)
// encW3 [64][16] @4608 (w3row0[8] w3row1[8] per lane, C-layout rows)
// decW3 @5632    (total 6656 floats = 26.6 KB)
__global__ void prep_kernel(
    const float* __restrict__ ew1, const float* __restrict__ eb1,
    const float* __restrict__ ew2, const float* __restrict__ eb2,
    const float* __restrict__ ew3,
    const float* __restrict__ dw1, const float* __restrict__ db1,
    const float* __restrict__ dw2, const float* __restrict__ db2,
    const float* __restrict__ dw3,
    float* __restrict__ ws)
{
    const int t = threadIdx.x;
    if (t >= 64) return;
    const int h = t >> 5, m = t & 31;
    unsigned short* frag = (unsigned short*)(ws + 4096);
#pragma unroll
    for (int jj = 0; jj < 8; ++jj) {
        const int j = 8 * h + jj;
        ws[t*24 + jj]             = ew1[2*j];
        ws[t*24 + 8 + jj]         = ew1[2*j + 1];
        ws[t*24 + 16 + jj]        = eb1[j];
        ws[1536 + t*24 + jj]      = dw1[2*j];
        ws[1536 + t*24 + 8 + jj]  = dw1[2*j + 1];
        ws[1536 + t*24 + 16 + jj] = db1[j];
        frag[t*8 + jj]       = (m < 16) ? f2bf1(ew2[m*16 + j]) : (unsigned short)0;
        frag[512 + t*8 + jj] = (m < 16) ? f2bf1(dw2[m*16 + j]) : (unsigned short)0;
    }
#pragma unroll
    for (int r = 0; r < 8; ++r) {
        const int i = (r & 3) + 8 * (r >> 2) + 4 * h;   // C-layout row for reg r
        ws[3072 + t*8 + r] = eb2[i];
        ws[3584 + t*8 + r] = db2[i];
        ws[4608 + t*16 + r]     = ew3[i];        // w3[0, i]
        ws[4608 + t*16 + 8 + r] = ew3[16 + i];   // w3[1, i]
        ws[5632 + t*16 + r]     = dw3[i];
        ws[5632 + t*16 + 8 + r] = dw3[16 + i];
    }
}

__device__ __forceinline__ void mlp_mfma(
    const float* __restrict__ L1, const float* __restrict__ B2,
    const float* __restrict__ W3, bf16x8 A2, float b30, float b31,
    float x0, float x1,
    float& o0, float& o1, float& J00, float& J01, float& J10, float& J11)
{
    float h1[8], ta[8], tb[8];
#pragma unroll
    for (int jj = 0; jj < 8; ++jj) {
        float wa = L1[jj], wb = L1[8 + jj], bb = L1[16 + jj];
        float z = fmaf(wa, x0, fmaf(wb, x1, bb));
        float sp, sg; activ(z, sp, sg);
        h1[jj] = sp; ta[jj] = sg * wa; tb[jj] = sg * wb;
    }
    bf16x8 Bh = pack8(h1), Bta = pack8(ta), Btb = pack8(tb);
    f32x16 Z;
#pragma unroll
    for (int r = 0; r < 16; ++r) Z[r] = 0.0f;

    f32x16 zc = __builtin_amdgcn_mfma_f32_32x32x16_bf16(A2, Bh, Z, 0, 0, 0);
    float sp2[8], sg2[8];
#pragma unroll
    for (int r = 0; r < 8; ++r) {
        float z = zc[r] + B2[r];
        activ(z, sp2[r], sg2[r]);
    }
    f32x16 ua = __builtin_amdgcn_mfma_f32_32x32x16_bf16(A2, Bta, Z, 0, 0, 0);

    // layer-3 outputs: per-lane partial over this half's 8 rows + butterfly
    float a0 = 0.0f, a1 = 0.0f;
#pragma unroll
    for (int r = 0; r < 8; ++r) {
        a0 = fmaf(W3[r], sp2[r], a0);
        a1 = fmaf(W3[8 + r], sp2[r], a1);
    }
    o0 = a0 + __shfl_xor(a0, 32) + b30;
    o1 = a1 + __shfl_xor(a1, 32) + b31;

    float sa[8];
#pragma unroll
    for (int r = 0; r < 8; ++r) sa[r] = sg2[r] * ua[r];
    f32x16 ub = __builtin_amdgcn_mfma_f32_32x32x16_bf16(A2, Btb, Z, 0, 0, 0);

    float p0 = 0.0f, p1 = 0.0f;
#pragma unroll
    for (int r = 0; r < 8; ++r) {
        p0 = fmaf(W3[r], sa[r], p0);
        p1 = fmaf(W3[8 + r], sa[r], p1);
    }
    J00 = p0 + __shfl_xor(p0, 32);
    J10 = p1 + __shfl_xor(p1, 32);

    float sb[8];
#pragma unroll
    for (int r = 0; r < 8; ++r) sb[r] = sg2[r] * ub[r];
    float q0 = 0.0f, q1 = 0.0f;
#pragma unroll
    for (int r = 0; r < 8; ++r) {
        q0 = fmaf(W3[r], sb[r], q0);
        q1 = fmaf(W3[8 + r], sb[r], q1);
    }
    J01 = q0 + __shfl_xor(q0, 32);
    J11 = q1 + __shfl_xor(q1, 32);
}

__device__ __forceinline__ void do_group(
    const float* __restrict__ q, float* __restrict__ out, int n, int sbase,
    int s32, int h,
    const float* __restrict__ encL1, const float* __restrict__ decL1,
    const float* __restrict__ encB2, const float* __restrict__ decB2,
    const float* __restrict__ encW3, const float* __restrict__ decW3,
    bf16x8 A2e, bf16x8 A2d,
    float eb30, float eb31, float db30, float db31)
{
    const int sample = sbase + s32;
    const int sidx = sample < n ? sample : n - 1;

    const float2 qv = ((const float2*)q)[sidx];
    const float x = qv.x, y = qv.y;

    float th0, th1, eJ00, eJ01, eJ10, eJ11;
    mlp_mfma(encL1, encB2, encW3, A2e, eb30, eb31, x, y,
             th0, th1, eJ00, eJ01, eJ10, eJ11);
    // th/eJ valid in ALL lanes (butterfly) -> feeds dec directly

    float qh0, qh1, dJ00, dJ01, dJ10, dJ11;
    mlp_mfma(decL1, decB2, decW3, A2d, db30, db31, th0, th1,
             qh0, qh1, dJ00, dJ01, dJ10, dJ11);

    if (sample < n) {
        const size_t nn = (size_t)n;
        if (h == 0) {
            ((float2*)(out))[sample]          = make_float2(th0, th1);
            ((float4*)(out + 2 * nn))[sample] = make_float4(eJ00, eJ01, eJ10, eJ11);
        } else {
            const float r2   = fmaf(x, x, y * y);
            const float iv   = __builtin_amdgcn_rcpf(r2);
            const float rinv = __builtin_amdgcn_rsqf(r2 + 1e-8f);
            ((float2*)(out + 6 * nn))[sample]  = make_float2(qh0, qh1);
            ((float4*)(out + 8 * nn))[sample]  = make_float4(dJ00, dJ01, dJ10, dJ11);
            ((float4*)(out + 12 * nn))[sample] = make_float4(-y * iv, x * iv, x * rinv, y * rinv);
        }
    }
}

__global__ __launch_bounds__(256) void ae_mfma_kernel(
    const float* __restrict__ q,
    const float* __restrict__ eb3, const float* __restrict__ db3,
    const float* __restrict__ ws, float* __restrict__ out, int n)
{
    const int lane = threadIdx.x & 63;
    const int w = blockIdx.x * 4 + (threadIdx.x >> 6);
    const int s32 = lane & 31, h = lane >> 5;
    const long base = (long)w * 64;            // 64 samples per wave
    if (base >= n) return;                     // wave-uniform exit

    const float* encL1 = ws + (size_t)lane * 24;
    const float* decL1 = ws + 1536 + (size_t)lane * 24;
    const float* encB2 = ws + 3072 + (size_t)lane * 8;
    const float* decB2 = ws + 3584 + (size_t)lane * 8;
    const float* encW3 = ws + 4608 + (size_t)lane * 16;
    const float* decW3 = ws + 5632 + (size_t)lane * 16;
    const bf16x8* fr = (const bf16x8*)(ws + 4096);
    const bf16x8 A2e = fr[lane], A2d = fr[64 + lane];
    const float eb30 = eb3[0], eb31 = eb3[1];
    const float db30 = db3[0], db31 = db3[1];

    do_group(q, out, n, (int)base, s32, h, encL1, decL1, encB2, decB2,
             encW3, decW3, A2e, A2d, eb30, eb31, db30, db31);
    if (base + 32 < n)
        do_group(q, out, n, (int)base + 32, s32, h, encL1, decL1, encB2, decB2,
                 encW3, decW3, A2e, A2d, eb30, eb31, db30, db31);
}

extern "C" void kernel_launch(void* const* d_in, const int* in_sizes, int n_in,
                              void* d_out, int out_size, void* d_ws, size_t ws_size,
                              hipStream_t stream)
{
    const float* q   = (const float*)d_in[0];
    const float* ew1 = (const float*)d_in[1];
    const float* eb1 = (const float*)d_in[2];
    const float* ew2 = (const float*)d_in[3];
    const float* eb2 = (const float*)d_in[4];
    const float* ew3 = (const float*)d_in[5];
    const float* eb3 = (const float*)d_in[6];
    const float* dw1 = (const float*)d_in[7];
    const float* db1 = (const float*)d_in[8];
    const float* dw2 = (const float*)d_in[9];
    const float* db2 = (const float*)d_in[10];
    const float* dw3 = (const float*)d_in[11];
    const float* db3 = (const float*)d_in[12];

    const int n = in_sizes[0] / 2;
    float* ws = (float*)d_ws;

    prep_kernel<<<1, 64, 0, stream>>>(ew1, eb1, ew2, eb2, ew3,
                                      dw1, db1, dw2, db2, dw3, ws);

    const int waves  = (n + 63) / 64;
    const int blocks = (waves + 3) / 4;
    ae_mfma_kernel<<<blocks, 256, 0, stream>>>(q, eb3, db3, ws, (float*)d_out, n);
}